// Round 6
// baseline (573.885 us; speedup 1.0000x reference)
//
#include <hip/hip_runtime.h>
#include <hip/hip_bf16.h>
#include <cstdint>

// ---------------------------------------------------------------------------
// LinearAttention on MI355X (gfx950)
// L=4096, N=4, E=1024, H=16, D=64.  M = L*N = 16384.
// Round 10 (= R9 with the macro token-paste bug fixed): fuse fp32->bf16
// A-conversion INTO the projection GEMMs (removes the 3 convert dispatches =
// ~300 MB HBM traffic). gemm_bt<MODE,AF32>:
//   AF32=1: A reg-staged fp32 (T14 issue-early/write-late): ph0 issues
//     A-hi(u+1) dwordx4 loads + B-hi(u+1) gload_lds; ph1 writes A-lo(u+1)
//     (cvt_pk + swizzled ds_write, loads issued prev ph3); ph2 stages
//     B-lo(u+2) gload; ph3 issues A-lo(u+2) + writes A-hi(u+1).
//     Boundary s_waitcnt vmcnt(6) (leaves B-lo + A-lo of u+2 in flight).
//     Conversion = v_cvt_pk_bf16_f32 inline asm (8 ops/half-tile).
//   AF32=0: R4's verified gload_lds path (final GEMM, A = bf16 out1).
// Slot WAR analysis: every write lands >=2 barriers after its slot's last
// read. attn_out (R7 MFMA) and other kernels unchanged.
// ---------------------------------------------------------------------------

typedef __attribute__((ext_vector_type(8))) short bf16x8;
typedef __attribute__((ext_vector_type(4))) float f32x4;

#define L_SEQ 4096
#define NBATCH 4
#define EMB 1024
#define NHEADS 16
#define HDIM 64
#define MROWS (L_SEQ * NBATCH)   // 16384
#define NHG (NBATCH * NHEADS)    // 64 head-groups
#define LCHUNK 512
#define NCHUNK (L_SEQ / LCHUNK)  // 8

__device__ __forceinline__ unsigned short f2bf(float f) {
  union { float f; uint32_t u; } v; v.f = f;
  uint32_t u = v.u;
  u += 0x7fffu + ((u >> 16) & 1u);   // round-to-nearest-even
  return (unsigned short)(u >> 16);
}
__device__ __forceinline__ float bf2f(unsigned short s) {
  union { uint32_t u; float f; } v; v.u = ((uint32_t)s) << 16;
  return v.f;
}
__device__ __forceinline__ uint32_t pkbf(float a, float b) {
  union { float f; uint32_t u; } ua, ub; ua.f = a; ub.f = b;
  return ((ua.u + 0x8000u) >> 16) | ((ub.u + 0x8000u) & 0xffff0000u);
}

// ---------------- fp32 -> bf16 convert, 4 weight matrices in one dispatch ---
__global__ __launch_bounds__(256) void convert_w4(const float* __restrict__ s0,
                                                  const float* __restrict__ s1,
                                                  const float* __restrict__ s2,
                                                  const float* __restrict__ s3,
                                                  unsigned short* __restrict__ d0,
                                                  unsigned short* __restrict__ d1,
                                                  unsigned short* __restrict__ d2,
                                                  unsigned short* __restrict__ d3,
                                                  int n) {
  const int w = blockIdx.y;
  const float* src = (w == 0) ? s0 : (w == 1) ? s1 : (w == 2) ? s2 : s3;
  unsigned short* dst = (w == 0) ? d0 : (w == 1) ? d1 : (w == 2) ? d2 : d3;
  int i = (blockIdx.x * 256 + threadIdx.x) * 4;
  if (i + 4 <= n) {
    float4 f = *(const float4*)(src + i);
    uint2 p;
    p.x = pkbf(f.x, f.y);
    p.y = pkbf(f.z, f.w);
    *(uint2*)(dst + i) = p;
  }
}

// ---------------- bf16 MFMA GEMM: C = A(MxK) . B(NnxK)^T + bias -------------
// MODE 0: elu(x)+1 -> bf16 ; MODE 1: x -> bf16 ; MODE 2: x -> fp32
// AF32 1: A read as fp32 (reg-staged + cvt_pk); 0: A bf16 via gload_lds.
// M % 256 == 0, Nn % 256 == 0, K % 128 == 0 (NT = K/64 even, >= 4).
// 512 threads (8 waves: wr = wid>>2 -> M half; wc = wid&3 -> N quarter).
// LDS: A half-slots s*16384 (s=0..3), B half-slots 65536 + s*16384 (128 KB).
// Tile t uses slots (2t)&3 (lo rows 0-127) and +1 (hi rows 128-255).
// Swizzle: within a 128 B row, byte ^= ((row&7)<<4).

// stage one 128x64 half-tile via gload_lds: MATB 0=A/1=B, RH row-half.
#define STAGE_H(MATB, RH, SLOT, KTN)                                            \
  do {                                                                          \
    _Pragma("unroll")                                                           \
    for (int r_ = 0; r_ < 2; r_++) {                                            \
      const long grow_ = ((MATB) ? bcol0 : arow0) + (RH) * 128 + r_ * 64 + srowt;\
      const unsigned short* gp_ =                                               \
          ((MATB) ? B : A) + grow_ * (long)K + (KTN) + skoff;                   \
      __builtin_amdgcn_global_load_lds(                                         \
          (const __attribute__((address_space(1))) void*)gp_,                   \
          (__attribute__((address_space(3))) void*)(smem + (MATB) * 65536 +     \
              (SLOT) * 16384 + r_ * 8192 + wid * 1024),                         \
          16, 0, 0);                                                            \
    }                                                                           \
  } while (0)

// issue 4 float4 loads of an A fp32 half-tile into float4 P[4] (const idx)
#define ISSUE_A32(P, RH, KTN)                                                   \
  do {                                                                          \
    const float* gpa_ = A32 + (arow0 + (RH) * 128 + srowt) * (long)K + (KTN) +  \
                        (tid & 7) * 8;                                          \
    const float* gpb_ = A32 + (arow0 + (RH) * 128 + 64 + srowt) * (long)K +     \
                        (KTN) + (tid & 7) * 8;                                  \
    P[0] = *(const float4*)gpa_;                                                \
    P[1] = *(const float4*)(gpa_ + 4);                                          \
    P[2] = *(const float4*)gpb_;                                                \
    P[3] = *(const float4*)(gpb_ + 4);                                          \
  } while (0)

#define CVTPK(D, X, Y)                                                          \
  asm("v_cvt_pk_bf16_f32 %0, %1, %2" : "=v"(D) : "v"(X), "v"(Y))

// convert P[0..3] (16 floats) and write as swizzled bf16 into A slot SLOT
#define WRITE_A32(P, SLOT)                                                      \
  do {                                                                          \
    uint32_t c0_, c1_, c2_, c3_, c4_, c5_, c6_, c7_;                            \
    CVTPK(c0_, P[0].x, P[0].y); CVTPK(c1_, P[0].z, P[0].w);                     \
    CVTPK(c2_, P[1].x, P[1].y); CVTPK(c3_, P[1].z, P[1].w);                     \
    CVTPK(c4_, P[2].x, P[2].y); CVTPK(c5_, P[2].z, P[2].w);                     \
    CVTPK(c6_, P[3].x, P[3].y); CVTPK(c7_, P[3].z, P[3].w);                     \
    char* db_ = smem + (SLOT) * 16384 + srowt * 128 +                           \
                (((tid & 7) * 16) ^ ((srowt & 7) << 4));                        \
    *(uint4*)db_ = make_uint4(c0_, c1_, c2_, c3_);                              \
    *(uint4*)(db_ + 8192) = make_uint4(c4_, c5_, c6_, c7_);                     \
  } while (0)

// one 16-MFMA cluster: C quadrant rows MFB..MFB+3 x cols NFB..NFB+1, K=64
#define MFMA_Q(AF, BF, MFB, NFB)                                                \
  do {                                                                          \
    __builtin_amdgcn_s_setprio(1);                                              \
    _Pragma("unroll")                                                           \
    for (int mi_ = 0; mi_ < 4; mi_++)                                           \
      _Pragma("unroll")                                                         \
      for (int ni_ = 0; ni_ < 2; ni_++)                                         \
        _Pragma("unroll")                                                       \
        for (int ks_ = 0; ks_ < 2; ks_++)                                       \
          acc[(MFB) + mi_][(NFB) + ni_] =                                       \
              __builtin_amdgcn_mfma_f32_16x16x32_bf16(                          \
                  AF[mi_ * 2 + ks_], BF[ni_ * 2 + ks_],                         \
                  acc[(MFB) + mi_][(NFB) + ni_], 0, 0, 0);                      \
    __builtin_amdgcn_s_setprio(0);                                              \
  } while (0)

#define PH_SYNC                                                                 \
  __builtin_amdgcn_s_barrier();                                                 \
  asm volatile("s_waitcnt lgkmcnt(0)" ::: "memory");                            \
  __builtin_amdgcn_sched_barrier(0);

// one K-tile u (A/B lo slots at SA, hi at SA+1; SA = (2u)&3).
// AF32=1: ph0 issue A-hi(u+1)+stage B-hi(u+1); ph1 write A-lo(u+1) [regs from
//         prev ph3]; ph2 stage B-lo(u+2); ph3 issue A-lo(u+2)+write A-hi(u+1).
// AF32=0: R4 stream: ph0 A-hi(u+1) gload, ph1 B-hi(u+1), ph2 B-lo(u+2),
//         ph3 A-lo(u+2).
// VMODE: 1 = counted boundary (vmcnt 6/4), 2 = vmcnt(0), 0 = none.
#define TILE_T(SA, K1, K2, S01, S23, WA1, VMODE)                                \
  do {                                                                          \
    bf16x8 af0[8], af1[8], bf0[4], bf1[4];                                      \
    float4 ah_[4];                                                              \
    /* ph0: read A rows 0-63 (of wave's half) + B lo rows */                    \
    _Pragma("unroll")                                                           \
    for (int mi_ = 0; mi_ < 4; mi_++)                                           \
      _Pragma("unroll")                                                         \
      for (int ks_ = 0; ks_ < 2; ks_++)                                         \
        af0[mi_ * 2 + ks_] = *(const bf16x8*)(smem + ((SA) + wr) * 16384 + aRB +\
                                              mi_ * 2048 + akt[ks_]);           \
    _Pragma("unroll")                                                           \
    for (int ni_ = 0; ni_ < 2; ni_++)                                           \
      _Pragma("unroll")                                                         \
      for (int ks_ = 0; ks_ < 2; ks_++)                                         \
        bf0[ni_ * 2 + ks_] = *(const bf16x8*)(smem + 65536 +                    \
                                              ((SA) + (wc >> 1)) * 16384 + bRB +\
                                              ni_ * 2048 + akt[ks_]);           \
    if constexpr (AF32) {                                                       \
      if (S01) { ISSUE_A32(ah_, 1, K1); STAGE_H(1, 1, (SA) ^ 3, K1); }          \
    } else {                                                                    \
      if (S01) STAGE_H(0, 1, (SA) ^ 3, K1);                                     \
    }                                                                           \
    PH_SYNC                                                                     \
    MFMA_Q(af0, bf0, 0, 0);                                                     \
    __builtin_amdgcn_s_barrier();                                               \
    /* ph1: read B hi rows */                                                   \
    _Pragma("unroll")                                                           \
    for (int ni_ = 0; ni_ < 2; ni_++)                                           \
      _Pragma("unroll")                                                         \
      for (int ks_ = 0; ks_ < 2; ks_++)                                         \
        bf1[ni_ * 2 + ks_] = *(const bf16x8*)(smem + 65536 +                    \
                                              ((SA) + (wc >> 1)) * 16384 + bRB +\
                                              (ni_ + 2) * 2048 + akt[ks_]);     \
    if constexpr (AF32) {                                                       \
      if (WA1) WRITE_A32(ap_, (SA) ^ 2);                                        \
    } else {                                                                    \
      if (S01) STAGE_H(1, 1, (SA) ^ 3, K1);                                     \
    }                                                                           \
    PH_SYNC                                                                     \
    MFMA_Q(af0, bf1, 0, 2);                                                     \
    __builtin_amdgcn_s_barrier();                                               \
    /* ph2: read A rows 64-127; stage B-lo(u+2) */                              \
    _Pragma("unroll")                                                           \
    for (int mi_ = 0; mi_ < 4; mi_++)                                           \
      _Pragma("unroll")                                                         \
      for (int ks_ = 0; ks_ < 2; ks_++)                                         \
        af1[mi_ * 2 + ks_] = *(const bf16x8*)(smem + ((SA) + wr) * 16384 + aRB +\
                                              (mi_ + 4) * 2048 + akt[ks_]);     \
    if (S23) STAGE_H(1, 0, (SA), K2);                                           \
    PH_SYNC                                                                     \
    MFMA_Q(af1, bf1, 4, 2);                                                     \
    __builtin_amdgcn_s_barrier();                                               \
    /* ph3: issue A-lo(u+2); write A-hi(u+1); counted boundary wait */          \
    if constexpr (AF32) {                                                       \
      if (S23) ISSUE_A32(ap_, 0, K2);                                           \
      if (S01) WRITE_A32(ah_, (SA) ^ 3);                                        \
    } else {                                                                    \
      if (S23) STAGE_H(0, 0, (SA), K2);                                         \
    }                                                                           \
    PH_SYNC                                                                     \
    MFMA_Q(af1, bf0, 4, 0);                                                     \
    if ((VMODE) == 1) {                                                         \
      if constexpr (AF32) asm volatile("s_waitcnt vmcnt(6)" ::: "memory");      \
      else                asm volatile("s_waitcnt vmcnt(4)" ::: "memory");      \
    }                                                                           \
    if ((VMODE) == 2) asm volatile("s_waitcnt vmcnt(0)" ::: "memory");          \
    __builtin_amdgcn_s_barrier();                                               \
  } while (0)

template <int MODE, int AF32>
__global__ __launch_bounds__(512, 2) void gemm_bt(const unsigned short* __restrict__ A,
                                                  const float* __restrict__ A32,
                                                  const unsigned short* __restrict__ B,
                                                  const float* __restrict__ bias,
                                                  void* __restrict__ Cout,
                                                  int M, int Nn, int K) {
  __shared__ __align__(16) char smem[131072];

  const int tid   = threadIdx.x;
  const int wid   = tid >> 6;
  const int lane  = tid & 63;
  const int col16 = lane & 15;
  const int quad  = lane >> 4;
  const int wr = wid >> 2;       // 0..1 : M half (rows wr*128..+127)
  const int wc = wid & 3;        // 0..3 : N quarter (cols wc*64..+63)
  const long arow0 = (long)blockIdx.x * 256;
  const long bcol0 = (long)blockIdx.y * 256;

  // ---- read-address constants (swizzled) ----
  const int axor = (col16 & 7) << 4;
  int akt[2];
  akt[0] = (quad * 16) ^ axor;
  akt[1] = (64 + quad * 16) ^ axor;
  const int aRB = col16 * 128;                    // within-slot A row base
  const int bRB = ((wc & 1) * 64 + col16) * 128;  // within-slot B row base

  // ---- staging constants ----
  const int srowt = tid >> 3;                                      // 0..63
  const int skoff = (((tid & 7) * 16) ^ ((srowt & 7) << 4)) >> 1;  // shorts

  const int NT = K >> 6;   // K-tiles of 64 (even, >= 4)

  // in-flight A-lo fp32 regs (issued ph3, written next ph1)
  float4 ap_[4];

  const f32x4 fzero = {0.f, 0.f, 0.f, 0.f};
  f32x4 acc[8][4];

  if constexpr (AF32) {
    // prologue: A(0) both halves inline (load+cvt+write), B(0) + B-lo(1)
    // gloads, issue A-lo(1) regs.
    {
      float4 aw_[4];
      ISSUE_A32(aw_, 0, 0);  WRITE_A32(aw_, 0);   // A-lo(0) -> slot0
      ISSUE_A32(aw_, 1, 0);  WRITE_A32(aw_, 1);   // A-hi(0) -> slot1
    }
    STAGE_H(1, 0, 0, 0);      // B-lo(0) -> B-slot0
    STAGE_H(1, 1, 1, 0);      // B-hi(0) -> B-slot1
    STAGE_H(1, 0, 2, 64);     // B-lo(1) -> B-slot2
    ISSUE_A32(ap_, 0, 64);    // A-lo(1) regs
#pragma unroll
    for (int i = 0; i < 8; i++)
#pragma unroll
      for (int j = 0; j < 4; j++) acc[i][j] = fzero;
    asm volatile("s_waitcnt vmcnt(6)" ::: "memory");   // B(0) lo+hi resident
    asm volatile("s_waitcnt lgkmcnt(0)" ::: "memory"); // our ds_writes drained
    __builtin_amdgcn_s_barrier();
  } else {
    // R4 prologue: tile0 all 4 halves + B-lo(1) + A-lo(1) via gload_lds
    STAGE_H(0, 0, 0, 0);      // A-lo(0)
    STAGE_H(0, 1, 1, 0);      // A-hi(0)
    STAGE_H(1, 0, 0, 0);      // B-lo(0)
    STAGE_H(1, 1, 1, 0);      // B-hi(0)
    STAGE_H(1, 0, 2, 64);     // B-lo(1)
    STAGE_H(0, 0, 2, 64);     // A-lo(1)
#pragma unroll
    for (int i = 0; i < 8; i++)
#pragma unroll
      for (int j = 0; j < 4; j++) acc[i][j] = fzero;
    asm volatile("s_waitcnt vmcnt(4)" ::: "memory");   // tile 0 resident
    __builtin_amdgcn_s_barrier();
  }

  // main loop: full-stage tiles 0..NT-3 in pairs
#pragma unroll 1
  for (int u = 0; u + 4 <= NT; u += 2) {
    TILE_T(0, (u + 1) * 64, (u + 2) * 64, 1, 1, 1, 1);
    TILE_T(2, (u + 2) * 64, (u + 3) * 64, 1, 1, 1, 1);
  }
  // tail: tile NT-2 (stages tile NT-1's hi halves + writes its lo), NT-1 bare
  TILE_T(0, (NT - 1) * 64, 0, 1, 0, 1, 2);
  TILE_T(2, 0, 0, 0, 0, 0, 0);

  // ---- epilogue: 8 slabs of 32 rows x 256 cols through LDS ----
  float bcol[4];
#pragma unroll
  for (int nf = 0; nf < 4; nf++) bcol[nf] = bias[bcol0 + wc * 64 + nf * 16 + col16];

  const int erow = tid >> 4;   // 0..31
  const int ecc  = tid & 15;   // 16-col chunk

  if (MODE != 2) {
    unsigned short* epi = (unsigned short*)smem;
    const int EST = 264;  // shorts; 528 B row stride
#pragma unroll
    for (int s = 0; s < 8; s++) {
      if ((s >> 2) == wr) {
        const int mfb = (s & 3) * 2;
#pragma unroll
        for (int ml = 0; ml < 2; ml++)
#pragma unroll
          for (int nf = 0; nf < 4; nf++)
#pragma unroll
            for (int rr = 0; rr < 4; rr++) {
              float vv = acc[mfb + ml][nf][rr] + bcol[nf];
              if (MODE == 0) vv = (vv > 0.f) ? (vv + 1.f) : __expf(vv);  // elu+1
              epi[(ml * 16 + quad * 4 + rr) * EST + wc * 64 + nf * 16 + col16] =
                  f2bf(vv);
            }
      }
      __syncthreads();
      {
        const long gr = arow0 + s * 32 + erow;
        const unsigned short* srcp = &epi[erow * EST + ecc * 16];
        uint4 a  = *(const uint4*)srcp;
        uint4 b2 = *(const uint4*)(srcp + 8);
        unsigned short* Cp = (unsigned short*)Cout + gr * Nn + bcol0 + ecc * 16;
        *(uint4*)Cp       = a;
        *(uint4*)(Cp + 8) = b2;
      }
      __syncthreads();
    }
  } else {
    float* epi = (float*)smem;
    const int ESF = 260;  // floats; 1040 B row stride
#pragma unroll
    for (int s = 0; s < 8; s++) {
      if ((s >> 2) == wr) {
        const int mfb = (s & 3) * 2;
#pragma unroll
        for (int ml = 0; ml < 2; ml++)
#pragma unroll
          for (int nf = 0; nf < 4; nf++)
#pragma unroll
            for (int rr = 0; rr < 4; rr++)
              epi[(ml * 16 + quad * 4 + rr) * ESF + wc * 64 + nf * 16 + col16] =
                  acc[mfb + ml][nf][rr] + bcol[nf];
      }
      __syncthreads();
      {
        const long gr = arow0 + s * 32 + erow;
        const float* srcp = &epi[erow * ESF + ecc * 16];
        float* Cp = (float*)Cout + gr * Nn + bcol0 + ecc * 16;
#pragma unroll
        for (int s4 = 0; s4 < 4; s4++)
          *(float4*)(Cp + s4 * 4) = *(const float4*)(srcp + s4 * 4);
      }
      __syncthreads();
    }
  }
}

// ---------------- kv partials: kv[d][e] = sum_l kf[l][d]*v[l][e] ------------
// grid (NHG, NCHUNK), block 256. Non-atomic partial outputs per chunk.
__global__ __launch_bounds__(256) void kv_partial_kernel(const unsigned short* __restrict__ kf,
                                                         const unsigned short* __restrict__ vp,
                                                         float* __restrict__ kvp,
                                                         float* __restrict__ ksp) {
  __shared__ float ks[32 * 64];
  __shared__ float vs[32 * 64];
  const int hg = blockIdx.x;
  const int chunk = blockIdx.y;
  const int n = hg >> 4, h = hg & 15;
  const int tid = threadIdx.x;
  const int td = tid >> 4, te = tid & 15;   // thread covers d=td*4..+3, e=te*4..+3
  const long hoff = (long)n * EMB + h * HDIM;
  const int l0 = chunk * LCHUNK;

  float acc[4][4];
#pragma unroll
  for (int i = 0; i < 4; i++)
#pragma unroll
    for (int j = 0; j < 4; j++) acc[i][j] = 0.f;
  float ksacc[4] = {0.f, 0.f, 0.f, 0.f};

  const int lrow = tid >> 3;         // 0..31
  const int dcol = (tid & 7) * 8;    // 0..56

  for (int ls = 0; ls < LCHUNK; ls += 32) {
    const long g = (long)(l0 + ls + lrow) * (NBATCH * EMB) + hoff + dcol;
    uint4 kr = *(const uint4*)(kf + g);
    uint4 vr = *(const uint4*)(vp + g);
    float* kd = &ks[lrow * 64 + dcol];
    float* vd = &vs[lrow * 64 + dcol];
    uint32_t ku[4] = {kr.x, kr.y, kr.z, kr.w};
    uint32_t vu[4] = {vr.x, vr.y, vr.z, vr.w};
#pragma unroll
    for (int t2 = 0; t2 < 4; t2++) {
      kd[2 * t2]     = bf2f((unsigned short)(ku[t2] & 0xffffu));
      kd[2 * t2 + 1] = bf2f((unsigned short)(ku[t2] >> 16));
      vd[2 * t2]     = bf2f((unsigned short)(vu[t2] & 0xffffu));
      vd[2 * t2 + 1] = bf2f((unsigned short)(vu[t2] >> 16));
    }
    __syncthreads();
#pragma unroll
    for (int l = 0; l < 32; l++) {
      float kq[4], vq[4];
      *(float4*)kq = *(const float4*)(&ks[l * 64 + td * 4]);
      *(float4*)vq = *(const float4*)(&vs[l * 64 + te * 4]);
#pragma unroll
      for (int i = 0; i < 4; i++) {
        ksacc[i] += kq[i];
#pragma unroll
        for (int j = 0; j < 4; j++) acc[i][j] += kq[i] * vq[j];
      }
    }
    __syncthreads();
  }
  float* outp = kvp + ((long)chunk * NHG + hg) * 4096;
#pragma unroll
  for (int i = 0; i < 4; i++)
#pragma unroll
    for (int j = 0; j < 4; j++)
      outp[(td * 4 + i) * 64 + te * 4 + j] = acc[i][j];
  if (te == 0) {
    float* o2 = ksp + ((long)chunk * NHG + hg) * 64;
#pragma unroll
    for (int i = 0; i < 4; i++) o2[td * 4 + i] = ksacc[i];
  }
}

// ---------------- out1 = (qf @ kv) * 1/(qf.ksum + eps), bf16 row-major ------
// grid (NHG, 16), block 256 (4 waves). MFMA version (R7).
__global__ __launch_bounds__(256) void attn_out_kernel(const unsigned short* __restrict__ qf,
                                                       const float* __restrict__ kvp,
                                                       const float* __restrict__ ksp,
                                                       unsigned short* __restrict__ out1) {
  __shared__ __align__(16) char smem[53248];
  const int hg = blockIdx.x;
  const int lc = blockIdx.y;
  const int n = hg >> 4, h = hg & 15;
  const int tid = threadIdx.x;
  const int wid = tid >> 6;
  const int lane = tid & 63;
  const int col16 = lane & 15;
  const int quad  = lane >> 4;
  const long lbase = (long)lc * 256;

  // ---- stage A = qf[lbase..+255][h*64..+63] via gload_lds (swizzled source)
#pragma unroll
  for (int r = 0; r < 8; r++) {
    const int row = r * 32 + (tid >> 3);
    const long l = lbase + row;
    const int sk = (((tid & 7) * 16) ^ ((row & 7) << 4)) >> 1;   // shorts
    const unsigned short* gp = qf + (l * NBATCH + n) * (long)EMB + h * HDIM + sk;
    __builtin_amdgcn_global_load_lds(
        (const __attribute__((address_space(1))) void*)gp,
        (__attribute__((address_space(3))) void*)(smem + r * 4096 + tid * 16),
        16, 0, 0);
  }

  // ---- build B: reduce kv partials, hi/lo split, transposed swizzled writes
  char* Bl = smem + 32768;
  for (int w = tid; w < 4096; w += 256) {
    const int d = w >> 6, e = w & 63;
    float s = 0.f;
#pragma unroll
    for (int c = 0; c < NCHUNK; c++) s += kvp[((long)c * NHG + hg) * 4096 + w];
    const unsigned short hi = f2bf(s);
    const unsigned short lo = f2bf(s - bf2f(hi));
    const int key = (e & 7) << 4;
    *(unsigned short*)(Bl + e * 256 + ((2 * d) ^ key))       = hi;
    *(unsigned short*)(Bl + e * 256 + ((128 + 2 * d) ^ key)) = lo;
  }
  if (tid < 64) {
    float s = 0.f;
#pragma unroll
    for (int c = 0; c < NCHUNK; c++) s += ksp[((long)c * NHG + hg) * 64 + tid];
    const unsigned short hi = f2bf(s);
    const unsigned short lo = f2bf(s - bf2f(hi));
    *(unsigned short*)(Bl + 64 * 256 + 2 * tid)       = hi;   // row 64: key=0
    *(unsigned short*)(Bl + 64 * 256 + 128 + 2 * tid) = lo;
  }
  {  // zero rows 65..79
    uint32_t* zb = (uint32_t*)(Bl + 65 * 256);
    for (int i = tid; i < 15 * 64; i += 256) zb[i] = 0u;
  }
  __syncthreads();

  // ---- MFMA: per wave 64 l-rows x 80 cols, logical K=128 (hi pass + lo pass)
  const int wl0 = wid * 64;
  const int akey = (col16 & 7) << 4;

  bf16x8 af[4][2];
#pragma unroll
  for (int mi = 0; mi < 4; mi++)
#pragma unroll
    for (int ks = 0; ks < 2; ks++)
      af[mi][ks] = *(const bf16x8*)(smem + (wl0 + mi * 16 + col16) * 128 +
                                    ((ks * 64 + quad * 16) ^ akey));

  const f32x4 fzero = {0.f, 0.f, 0.f, 0.f};
  f32x4 acc[4][5];
#pragma unroll
  for (int mi = 0; mi < 4; mi++)
#pragma unroll
    for (int nf = 0; nf < 5; nf++) acc[mi][nf] = fzero;

#pragma unroll
  for (int nf = 0; nf < 5; nf++) {
    bf16x8 bfr[4];
#pragma unroll
    for (int pass = 0; pass < 2; pass++)
#pragma unroll
      for (int ks = 0; ks < 2; ks++)
        bfr[pass * 2 + ks] = *(const bf16x8*)(Bl + (nf * 16 + col16) * 256 +
                                              ((pass * 128 + ks * 64 + quad * 16) ^ akey));
#pragma unroll
    for (int mi = 0; mi < 4; mi++)
#pragma unroll
      for (int pass = 0; pass < 2; pass++)
#pragma unroll
        for (int ks = 0; ks < 2; ks++)
          acc[mi][nf] = __builtin_amdgcn_mfma_f32_16x16x32_bf16(
              af[mi][ks], bfr[pass * 2 + ks], acc[mi][nf], 0, 0, 0);
  }

  __syncthreads();   // all A reads done; reuse A region as epilogue buffer

  // ---- epilogue: z from denom col (lane quad*16 holds col 64), swizzled LDS
  unsigned short* epi = (unsigned short*)smem;
#pragma unroll
  for (int mi = 0; mi < 4; mi++) {
#pragma unroll
    for (int rr = 0; rr < 4; rr++) {
      const float dv = __shfl(acc[mi][4][rr], lane & 48);
      const float z = 1.f / (dv + 1e-6f);
      const int row = wl0 + mi * 16 + quad * 4 + rr;
      const int key = (row & 7) << 4;
#pragma unroll
      for (int nf = 0; nf < 4; nf++)
        *(unsigned short*)((char*)epi + row * 128 +
                           (((nf * 16 + col16) * 2) ^ key)) =
            f2bf(acc[mi][nf][rr] * z);
    }
  }
  __syncthreads();

  // packed readback: thread -> one row chunk of 16 B per pass, 8 passes
#pragma unroll
  for (int r = 0; r < 8; r++) {
    const int row = r * 32 + (tid >> 3);
    const long l = lbase + row;
    const uint4 vv = *(const uint4*)((char*)epi + row * 128 +
                                     (((tid & 7) * 16) ^ ((row & 7) << 4)));
    *(uint4*)(out1 + (l * NBATCH + n) * (long)EMB + h * HDIM + (tid & 7) * 8) = vv;
  }
}

// ---------------------------------------------------------------------------
extern "C" void kernel_launch(void* const* d_in, const int* in_sizes, int n_in,
                              void* d_out, int out_size, void* d_ws, size_t ws_size,
                              hipStream_t stream) {
  const float* q  = (const float*)d_in[0];
  const float* k  = (const float*)d_in[1];
  const float* v  = (const float*)d_in[2];
  const float* Wq = (const float*)d_in[3];
  const float* bq = (const float*)d_in[4];
  const float* Wk = (const float*)d_in[5];
  const float* bk = (const float*)d_in[6];
  const float* Wv = (const float*)d_in[7];
  const float* bv = (const float*)d_in[8];
  const float* Wo = (const float*)d_in[9];
  const float* bo = (const float*)d_in[10];

  char* ws = (char*)d_ws;
  const size_t BUF = (size_t)MROWS * EMB * 2;  // 33,554,432 B
  unsigned short* T0  = (unsigned short*)(ws);              // out1
  unsigned short* qf  = (unsigned short*)(ws + BUF);
  unsigned short* kf  = (unsigned short*)(ws + 2 * BUF);
  unsigned short* vp  = (unsigned short*)(ws + 3 * BUF);
  unsigned short* Wqb = (unsigned short*)(ws + 4 * BUF);
  unsigned short* Wkb = Wqb + (size_t)EMB * EMB;
  unsigned short* Wvb = Wkb + (size_t)EMB * EMB;
  unsigned short* Wob = Wvb + (size_t)EMB * EMB;
  float* kvp = (float*)(ws + 4 * BUF + 4 * (size_t)EMB * EMB * 2);
  float* ksp = kvp + (size_t)NCHUNK * NHG * HDIM * HDIM;

  const int nW = EMB * EMB;       // 1,048,576

  // all 4 weight matrices -> bf16 in one dispatch
  convert_w4<<<dim3(nW / 1024, 4), 256, 0, stream>>>(Wq, Wk, Wv, Wo,
                                                     Wqb, Wkb, Wvb, Wob, nW);

  dim3 gg(MROWS / 256, EMB / 256), bb(512);

  // projections: fp32 inputs consumed directly (fused convert in A-staging)
  gemm_bt<0, 1><<<gg, bb, 0, stream>>>(nullptr, q, Wqb, bq, qf, MROWS, EMB, EMB);
  gemm_bt<0, 1><<<gg, bb, 0, stream>>>(nullptr, k, Wkb, bk, kf, MROWS, EMB, EMB);
  gemm_bt<1, 1><<<gg, bb, 0, stream>>>(nullptr, v, Wvb, bv, vp, MROWS, EMB, EMB);

  // attention state + output (out1 -> T0)
  kv_partial_kernel<<<dim3(NHG, NCHUNK), 256, 0, stream>>>(kf, vp, kvp, ksp);
  attn_out_kernel<<<dim3(NHG, L_SEQ / 256), 256, 0, stream>>>(qf, kvp, ksp, T0);

  // final projection -> fp32 output (A = bf16 out1, gload_lds path)
  gemm_bt<2, 0><<<gg, bb, 0, stream>>>(T0, nullptr, Wob, bo, d_out, MROWS, EMB, EMB);
}

// Round 7
// 453.536 us; speedup vs baseline: 1.2654x; 1.2654x over previous
//
#include <hip/hip_runtime.h>
#include <hip/hip_bf16.h>
#include <cstdint>

// ---------------------------------------------------------------------------
// LinearAttention on MI355X (gfx950)
// L=4096, N=4, E=1024, H=16, D=64.  M = L*N = 16384.
// Round 11: REVERT to R8/R4 configuration (best measured 461.9 us): separate
// convert dispatches + gemm_bt with 4 cycling half-tile slots and counted
// vmcnt(4) boundaries. The R9/R10 fused-convert (AF32) path is abandoned:
// +32 live VGPRs on a ~224-reg frag+acc footprint caused scratch spills
// (WRITE_SIZE 34->97 MB, +50 us/GEMM). One small change on top: attn_out's
// kvp reduction now uses float4 loads (32 dwordx4 vs 128 scalar dwords per
// thread) to shorten the serial reduce phase at kernel head.
// ---------------------------------------------------------------------------

typedef __attribute__((ext_vector_type(8))) short bf16x8;
typedef __attribute__((ext_vector_type(4))) float f32x4;

#define L_SEQ 4096
#define NBATCH 4
#define EMB 1024
#define NHEADS 16
#define HDIM 64
#define MROWS (L_SEQ * NBATCH)   // 16384
#define NHG (NBATCH * NHEADS)    // 64 head-groups
#define LCHUNK 512
#define NCHUNK (L_SEQ / LCHUNK)  // 8

__device__ __forceinline__ unsigned short f2bf(float f) {
  union { float f; uint32_t u; } v; v.f = f;
  uint32_t u = v.u;
  u += 0x7fffu + ((u >> 16) & 1u);   // round-to-nearest-even
  return (unsigned short)(u >> 16);
}
__device__ __forceinline__ float bf2f(unsigned short s) {
  union { uint32_t u; float f; } v; v.u = ((uint32_t)s) << 16;
  return v.f;
}
__device__ __forceinline__ uint32_t pkbf(float a, float b) {
  union { float f; uint32_t u; } ua, ub; ua.f = a; ub.f = b;
  return ((ua.u + 0x8000u) >> 16) | ((ub.u + 0x8000u) & 0xffff0000u);
}

// ---------------- fp32 -> bf16 convert ---------------------------------------
__global__ __launch_bounds__(256) void convert_kernel(const float* __restrict__ src,
                                                      unsigned short* __restrict__ dst,
                                                      int n) {
  int i = (blockIdx.x * 256 + threadIdx.x) * 4;
  if (i + 4 <= n) {
    float4 f = *(const float4*)(src + i);
    uint2 p;
    p.x = pkbf(f.x, f.y);
    p.y = pkbf(f.z, f.w);
    *(uint2*)(dst + i) = p;
  }
}

// ---------------- fp32 -> bf16 convert, 4 weight matrices in one dispatch ---
__global__ __launch_bounds__(256) void convert_w4(const float* __restrict__ s0,
                                                  const float* __restrict__ s1,
                                                  const float* __restrict__ s2,
                                                  const float* __restrict__ s3,
                                                  unsigned short* __restrict__ d0,
                                                  unsigned short* __restrict__ d1,
                                                  unsigned short* __restrict__ d2,
                                                  unsigned short* __restrict__ d3,
                                                  int n) {
  const int w = blockIdx.y;
  const float* src = (w == 0) ? s0 : (w == 1) ? s1 : (w == 2) ? s2 : s3;
  unsigned short* dst = (w == 0) ? d0 : (w == 1) ? d1 : (w == 2) ? d2 : d3;
  int i = (blockIdx.x * 256 + threadIdx.x) * 4;
  if (i + 4 <= n) {
    float4 f = *(const float4*)(src + i);
    uint2 p;
    p.x = pkbf(f.x, f.y);
    p.y = pkbf(f.z, f.w);
    *(uint2*)(dst + i) = p;
  }
}

// ---------------- bf16 MFMA GEMM: C = A(MxK) . B(NnxK)^T + bias -------------
// MODE 0: elu(x)+1 -> bf16 ; MODE 1: x -> bf16 ; MODE 2: x -> fp32
// M % 256 == 0, Nn % 256 == 0, K % 128 == 0 (NT = K/64 even, >= 4).
// 512 threads (8 waves: wr = wid>>2 in {0,1} -> M; wc = wid&3 -> N).
// LDS: A half-slots s*16384 (s=0..3), B half-slots 65536 + s*16384 (128 KB).
// Half-tile (128 rows x 64 k) of tile u, half h lives in slot (2u+h)&3.
// Swizzle: within a 128 B row, byte ^= ((row&7)<<4) (involution; applied to
// the gload_lds GLOBAL source and to ds_read addresses; LDS dest stays linear).

// stage one 128x64 half-tile: MATB 0=A/1=B, RH row-half, SLOT, KTN k-offset.
#define STAGE_H(MATB, RH, SLOT, KTN)                                            \
  do {                                                                          \
    _Pragma("unroll")                                                           \
    for (int r_ = 0; r_ < 2; r_++) {                                            \
      const long grow_ = ((MATB) ? bcol0 : arow0) + (RH) * 128 + r_ * 64 + srowt;\
      const unsigned short* gp_ =                                               \
          ((MATB) ? B : A) + grow_ * (long)K + (KTN) + skoff;                   \
      __builtin_amdgcn_global_load_lds(                                         \
          (const __attribute__((address_space(1))) void*)gp_,                   \
          (__attribute__((address_space(3))) void*)(smem + (MATB) * 65536 +     \
              (SLOT) * 16384 + r_ * 8192 + wid * 1024),                         \
          16, 0, 0);                                                            \
    }                                                                           \
  } while (0)

// one 16-MFMA cluster: C quadrant rows MFB..MFB+3 x cols NFB..NFB+1, K=64
#define MFMA_Q(AF, BF, MFB, NFB)                                                \
  do {                                                                          \
    __builtin_amdgcn_s_setprio(1);                                              \
    _Pragma("unroll")                                                           \
    for (int mi_ = 0; mi_ < 4; mi_++)                                           \
      _Pragma("unroll")                                                         \
      for (int ni_ = 0; ni_ < 2; ni_++)                                         \
        _Pragma("unroll")                                                       \
        for (int ks_ = 0; ks_ < 2; ks_++)                                       \
          acc[(MFB) + mi_][(NFB) + ni_] =                                       \
              __builtin_amdgcn_mfma_f32_16x16x32_bf16(                          \
                  AF[mi_ * 2 + ks_], BF[ni_ * 2 + ks_],                         \
                  acc[(MFB) + mi_][(NFB) + ni_], 0, 0, 0);                      \
    __builtin_amdgcn_s_setprio(0);                                              \
  } while (0)

#define PH_SYNC                                                                 \
  __builtin_amdgcn_s_barrier();                                                 \
  asm volatile("s_waitcnt lgkmcnt(0)" ::: "memory");                            \
  __builtin_amdgcn_sched_barrier(0);

// one K-tile u (A/B lo slots at SA, hi at SA+1; SA in {0,2} = (2u)&3).
// Stages: ph0 A-hi(u+1)->slot SA^3 (iff S01), ph1 B-hi(u+1)->SA^3 (iff S01),
//         ph2 B-lo(u+2)->SA (iff S23),        ph3 A-lo(u+2)->SA (iff S23).
// VMODE: 1 = boundary vmcnt(4) (steady), 2 = vmcnt(0) (tail fill), 0 = none.
#define TILE_T(SA, K1, K2, S01, S23, VMODE)                                     \
  do {                                                                          \
    bf16x8 af0[8], af1[8], bf0[4], bf1[4];                                      \
    /* ph0: read A rows 0-63 of half wr + B rows lo; stage A-hi(u+1) */         \
    _Pragma("unroll")                                                           \
    for (int mi_ = 0; mi_ < 4; mi_++)                                           \
      _Pragma("unroll")                                                         \
      for (int ks_ = 0; ks_ < 2; ks_++)                                         \
        af0[mi_ * 2 + ks_] = *(const bf16x8*)(smem + ((SA) + wr) * 16384 + aRB +\
                                              mi_ * 2048 + akt[ks_]);           \
    _Pragma("unroll")                                                           \
    for (int ni_ = 0; ni_ < 2; ni_++)                                           \
      _Pragma("unroll")                                                         \
      for (int ks_ = 0; ks_ < 2; ks_++)                                         \
        bf0[ni_ * 2 + ks_] = *(const bf16x8*)(smem + 65536 +                    \
                                              ((SA) + (wc >> 1)) * 16384 + bRB +\
                                              ni_ * 2048 + akt[ks_]);           \
    if (S01) STAGE_H(0, 1, (SA) ^ 3, K1);                                       \
    PH_SYNC                                                                     \
    MFMA_Q(af0, bf0, 0, 0);                                                     \
    __builtin_amdgcn_s_barrier();                                               \
    /* ph1: read B rows hi; stage B-hi(u+1) */                                  \
    _Pragma("unroll")                                                           \
    for (int ni_ = 0; ni_ < 2; ni_++)                                           \
      _Pragma("unroll")                                                         \
      for (int ks_ = 0; ks_ < 2; ks_++)                                         \
        bf1[ni_ * 2 + ks_] = *(const bf16x8*)(smem + 65536 +                    \
                                              ((SA) + (wc >> 1)) * 16384 + bRB +\
                                              (ni_ + 2) * 2048 + akt[ks_]);     \
    if (S01) STAGE_H(1, 1, (SA) ^ 3, K1);                                       \
    PH_SYNC                                                                     \
    MFMA_Q(af0, bf1, 0, 2);                                                     \
    __builtin_amdgcn_s_barrier();                                               \
    /* ph2: read A rows 64-127; stage B-lo(u+2) */                              \
    _Pragma("unroll")                                                           \
    for (int mi_ = 0; mi_ < 4; mi_++)                                           \
      _Pragma("unroll")                                                         \
      for (int ks_ = 0; ks_ < 2; ks_++)                                         \
        af1[mi_ * 2 + ks_] = *(const bf16x8*)(smem + ((SA) + wr) * 16384 + aRB +\
                                              (mi_ + 4) * 2048 + akt[ks_]);     \
    if (S23) STAGE_H(1, 0, (SA), K2);                                           \
    PH_SYNC                                                                     \
    MFMA_Q(af1, bf1, 4, 2);                                                     \
    __builtin_amdgcn_s_barrier();                                               \
    /* ph3: no reads; stage A-lo(u+2); counted boundary wait */                 \
    if (S23) STAGE_H(0, 0, (SA), K2);                                           \
    PH_SYNC                                                                     \
    MFMA_Q(af1, bf0, 4, 0);                                                     \
    if ((VMODE) == 1) asm volatile("s_waitcnt vmcnt(4)" ::: "memory");          \
    if ((VMODE) == 2) asm volatile("s_waitcnt vmcnt(0)" ::: "memory");          \
    __builtin_amdgcn_s_barrier();                                               \
  } while (0)

template <int MODE>
__global__ __launch_bounds__(512, 2) void gemm_bt(const unsigned short* __restrict__ A,
                                                  const unsigned short* __restrict__ B,
                                                  const float* __restrict__ bias,
                                                  void* __restrict__ Cout,
                                                  int M, int Nn, int K) {
  __shared__ __align__(16) char smem[131072];

  const int tid   = threadIdx.x;
  const int wid   = tid >> 6;
  const int lane  = tid & 63;
  const int col16 = lane & 15;
  const int quad  = lane >> 4;
  const int wr = wid >> 2;       // 0..1 : M half (rows wr*128..+127)
  const int wc = wid & 3;        // 0..3 : N quarter (cols wc*64..+63)
  const long arow0 = (long)blockIdx.x * 256;
  const long bcol0 = (long)blockIdx.y * 256;

  // ---- read-address constants (swizzled) ----
  const int axor = (col16 & 7) << 4;
  int akt[2];
  akt[0] = (quad * 16) ^ axor;
  akt[1] = (64 + quad * 16) ^ axor;
  const int aRB = col16 * 128;                    // within-slot A row base
  const int bRB = ((wc & 1) * 64 + col16) * 128;  // within-slot B row base

  // ---- staging constants (inverse-swizzled global source) ----
  const int srowt = tid >> 3;                                   // 0..63
  const int skoff = (((tid & 7) * 16) ^ ((srowt & 7) << 4)) >> 1;  // shorts

  const int NT = K >> 6;   // K-tiles of 64 (even, >= 4)

  // prologue: tile0 all 4 halves + B-lo(1) + A-lo(1)  (6 stage-ops, 12 loads)
  STAGE_H(0, 0, 0, 0);      // A-lo(0) -> A-slot0
  STAGE_H(0, 1, 1, 0);      // A-hi(0) -> A-slot1
  STAGE_H(1, 0, 0, 0);      // B-lo(0) -> B-slot0
  STAGE_H(1, 1, 1, 0);      // B-hi(0) -> B-slot1
  STAGE_H(1, 0, 2, 64);     // B-lo(1) -> B-slot2
  STAGE_H(0, 0, 2, 64);     // A-lo(1) -> A-slot2

  const f32x4 fzero = {0.f, 0.f, 0.f, 0.f};
  f32x4 acc[8][4];
#pragma unroll
  for (int i = 0; i < 8; i++)
#pragma unroll
    for (int j = 0; j < 4; j++) acc[i][j] = fzero;

  asm volatile("s_waitcnt vmcnt(4)" ::: "memory");  // tile 0 resident
  __builtin_amdgcn_s_barrier();

  // main loop: full-stage tiles 0..NT-3 in pairs
#pragma unroll 1
  for (int u = 0; u + 4 <= NT; u += 2) {
    TILE_T(0, (u + 1) * 64, (u + 2) * 64, 1, 1, 1);
    TILE_T(2, (u + 2) * 64, (u + 3) * 64, 1, 1, 1);
  }
  // tail: tile NT-2 stages only hi-halves of NT-1; tile NT-1 stages nothing
  TILE_T(0, (NT - 1) * 64, 0, 1, 0, 2);
  TILE_T(2, 0, 0, 0, 0, 0);

  // ---- epilogue: 8 slabs of 32 rows x 256 cols through LDS ----
  // C/D frag: row = quad*4 + rr, col = col16 (verified layout).
  float bcol[4];
#pragma unroll
  for (int nf = 0; nf < 4; nf++) bcol[nf] = bias[bcol0 + wc * 64 + nf * 16 + col16];

  const int erow = tid >> 4;   // 0..31
  const int ecc  = tid & 15;   // 16-col chunk

  if (MODE != 2) {
    unsigned short* epi = (unsigned short*)smem;
    const int EST = 264;  // shorts; 528 B row stride (16B-aligned, bank-skewed)
#pragma unroll
    for (int s = 0; s < 8; s++) {
      if ((s >> 2) == wr) {
        const int mfb = (s & 3) * 2;
#pragma unroll
        for (int ml = 0; ml < 2; ml++)
#pragma unroll
          for (int nf = 0; nf < 4; nf++)
#pragma unroll
            for (int rr = 0; rr < 4; rr++) {
              float vv = acc[mfb + ml][nf][rr] + bcol[nf];
              if (MODE == 0) vv = (vv > 0.f) ? (vv + 1.f) : __expf(vv);  // elu+1
              epi[(ml * 16 + quad * 4 + rr) * EST + wc * 64 + nf * 16 + col16] =
                  f2bf(vv);
            }
      }
      __syncthreads();
      {
        const long gr = arow0 + s * 32 + erow;
        const unsigned short* srcp = &epi[erow * EST + ecc * 16];
        uint4 a  = *(const uint4*)srcp;
        uint4 b2 = *(const uint4*)(srcp + 8);
        unsigned short* Cp = (unsigned short*)Cout + gr * Nn + bcol0 + ecc * 16;
        *(uint4*)Cp       = a;
        *(uint4*)(Cp + 8) = b2;
      }
      __syncthreads();
    }
  } else {
    float* epi = (float*)smem;
    const int ESF = 260;  // floats; 1040 B row stride (16B-aligned, bank-skewed)
#pragma unroll
    for (int s = 0; s < 8; s++) {
      if ((s >> 2) == wr) {
        const int mfb = (s & 3) * 2;
#pragma unroll
        for (int ml = 0; ml < 2; ml++)
#pragma unroll
          for (int nf = 0; nf < 4; nf++)
#pragma unroll
            for (int rr = 0; rr < 4; rr++)
              epi[(ml * 16 + quad * 4 + rr) * ESF + wc * 64 + nf * 16 + col16] =
                  acc[mfb + ml][nf][rr] + bcol[nf];
      }
      __syncthreads();
      {
        const long gr = arow0 + s * 32 + erow;
        const float* srcp = &epi[erow * ESF + ecc * 16];
        float* Cp = (float*)Cout + gr * Nn + bcol0 + ecc * 16;
#pragma unroll
        for (int s4 = 0; s4 < 4; s4++)
          *(float4*)(Cp + s4 * 4) = *(const float4*)(srcp + s4 * 4);
      }
      __syncthreads();
    }
  }
}

// ---------------- kv partials: kv[d][e] = sum_l kf[l][d]*v[l][e] ------------
// grid (NHG, NCHUNK), block 256. Non-atomic partial outputs per chunk.
__global__ __launch_bounds__(256) void kv_partial_kernel(const unsigned short* __restrict__ kf,
                                                         const unsigned short* __restrict__ vp,
                                                         float* __restrict__ kvp,
                                                         float* __restrict__ ksp) {
  __shared__ float ks[32 * 64];
  __shared__ float vs[32 * 64];
  const int hg = blockIdx.x;
  const int chunk = blockIdx.y;
  const int n = hg >> 4, h = hg & 15;
  const int tid = threadIdx.x;
  const int td = tid >> 4, te = tid & 15;   // thread covers d=td*4..+3, e=te*4..+3
  const long hoff = (long)n * EMB + h * HDIM;
  const int l0 = chunk * LCHUNK;

  float acc[4][4];
#pragma unroll
  for (int i = 0; i < 4; i++)
#pragma unroll
    for (int j = 0; j < 4; j++) acc[i][j] = 0.f;
  float ksacc[4] = {0.f, 0.f, 0.f, 0.f};

  const int lrow = tid >> 3;         // 0..31
  const int dcol = (tid & 7) * 8;    // 0..56

  for (int ls = 0; ls < LCHUNK; ls += 32) {
    const long g = (long)(l0 + ls + lrow) * (NBATCH * EMB) + hoff + dcol;
    uint4 kr = *(const uint4*)(kf + g);
    uint4 vr = *(const uint4*)(vp + g);
    float* kd = &ks[lrow * 64 + dcol];
    float* vd = &vs[lrow * 64 + dcol];
    uint32_t ku[4] = {kr.x, kr.y, kr.z, kr.w};
    uint32_t vu[4] = {vr.x, vr.y, vr.z, vr.w};
#pragma unroll
    for (int t2 = 0; t2 < 4; t2++) {
      kd[2 * t2]     = bf2f((unsigned short)(ku[t2] & 0xffffu));
      kd[2 * t2 + 1] = bf2f((unsigned short)(ku[t2] >> 16));
      vd[2 * t2]     = bf2f((unsigned short)(vu[t2] & 0xffffu));
      vd[2 * t2 + 1] = bf2f((unsigned short)(vu[t2] >> 16));
    }
    __syncthreads();
#pragma unroll
    for (int l = 0; l < 32; l++) {
      float kq[4], vq[4];
      *(float4*)kq = *(const float4*)(&ks[l * 64 + td * 4]);
      *(float4*)vq = *(const float4*)(&vs[l * 64 + te * 4]);
#pragma unroll
      for (int i = 0; i < 4; i++) {
        ksacc[i] += kq[i];
#pragma unroll
        for (int j = 0; j < 4; j++) acc[i][j] += kq[i] * vq[j];
      }
    }
    __syncthreads();
  }
  float* outp = kvp + ((long)chunk * NHG + hg) * 4096;
#pragma unroll
  for (int i = 0; i < 4; i++)
#pragma unroll
    for (int j = 0; j < 4; j++)
      outp[(td * 4 + i) * 64 + te * 4 + j] = acc[i][j];
  if (te == 0) {
    float* o2 = ksp + ((long)chunk * NHG + hg) * 64;
#pragma unroll
    for (int i = 0; i < 4; i++) o2[td * 4 + i] = ksacc[i];
  }
}

// ---------------- out1 = (qf @ kv) * 1/(qf.ksum + eps), bf16 row-major ------
// grid (NHG, 16), block 256 (4 waves). MFMA version (R7); kvp reduce now
// float4-vectorized (32 dwordx4 vs 128 scalar dword loads per thread).
__global__ __launch_bounds__(256) void attn_out_kernel(const unsigned short* __restrict__ qf,
                                                       const float* __restrict__ kvp,
                                                       const float* __restrict__ ksp,
                                                       unsigned short* __restrict__ out1) {
  __shared__ __align__(16) char smem[53248];
  const int hg = blockIdx.x;
  const int lc = blockIdx.y;
  const int n = hg >> 4, h = hg & 15;
  const int tid = threadIdx.x;
  const int wid = tid >> 6;
  const int lane = tid & 63;
  const int col16 = lane & 15;
  const int quad  = lane >> 4;
  const long lbase = (long)lc * 256;

  // ---- stage A = qf[lbase..+255][h*64..+63] via gload_lds (swizzled source)
#pragma unroll
  for (int r = 0; r < 8; r++) {
    const int row = r * 32 + (tid >> 3);
    const long l = lbase + row;
    const int sk = (((tid & 7) * 16) ^ ((row & 7) << 4)) >> 1;   // shorts
    const unsigned short* gp = qf + (l * NBATCH + n) * (long)EMB + h * HDIM + sk;
    __builtin_amdgcn_global_load_lds(
        (const __attribute__((address_space(1))) void*)gp,
        (__attribute__((address_space(3))) void*)(smem + r * 4096 + tid * 16),
        16, 0, 0);
  }

  // ---- build B: reduce kv partials (float4 loads), hi/lo split, transposed
  //      swizzled writes
  char* Bl = smem + 32768;
  for (int wb = tid * 4; wb < 4096; wb += 1024) {
    float4 s = make_float4(0.f, 0.f, 0.f, 0.f);
#pragma unroll
    for (int c = 0; c < NCHUNK; c++) {
      const float4 t = *(const float4*)(kvp + ((long)c * NHG + hg) * 4096 + wb);
      s.x += t.x; s.y += t.y; s.z += t.z; s.w += t.w;
    }
    const int d = wb >> 6;      // wb%64 in {0,4,..,60}: all 4 elems same d
    const int e0 = wb & 63;
    float sv[4] = {s.x, s.y, s.z, s.w};
#pragma unroll
    for (int j = 0; j < 4; j++) {
      const int e = e0 + j;
      const unsigned short hi = f2bf(sv[j]);
      const unsigned short lo = f2bf(sv[j] - bf2f(hi));
      const int key = (e & 7) << 4;
      *(unsigned short*)(Bl + e * 256 + ((2 * d) ^ key))       = hi;
      *(unsigned short*)(Bl + e * 256 + ((128 + 2 * d) ^ key)) = lo;
    }
  }
  if (tid < 64) {
    float s = 0.f;
#pragma unroll
    for (int c = 0; c < NCHUNK; c++) s += ksp[((long)c * NHG + hg) * 64 + tid];
    const unsigned short hi = f2bf(s);
    const unsigned short lo = f2bf(s - bf2f(hi));
    *(unsigned short*)(Bl + 64 * 256 + 2 * tid)       = hi;   // row 64: key=0
    *(unsigned short*)(Bl + 64 * 256 + 128 + 2 * tid) = lo;
  }
  {  // zero rows 65..79
    uint32_t* zb = (uint32_t*)(Bl + 65 * 256);
    for (int i = tid; i < 15 * 64; i += 256) zb[i] = 0u;
  }
  __syncthreads();

  // ---- MFMA: per wave 64 l-rows x 80 cols, logical K=128 (hi pass + lo pass)
  const int wl0 = wid * 64;
  const int akey = (col16 & 7) << 4;

  bf16x8 af[4][2];
#pragma unroll
  for (int mi = 0; mi < 4; mi++)
#pragma unroll
    for (int ks = 0; ks < 2; ks++)
      af[mi][ks] = *(const bf16x8*)(smem + (wl0 + mi * 16 + col16) * 128 +
                                    ((ks * 64 + quad * 16) ^ akey));

  const f32x4 fzero = {0.f, 0.f, 0.f, 0.f};
  f32x4 acc[4][5];
#pragma unroll
  for (int mi = 0; mi < 4; mi++)
#pragma unroll
    for (int nf = 0; nf < 5; nf++) acc[mi][nf] = fzero;

#pragma unroll
  for (int nf = 0; nf < 5; nf++) {
    bf16x8 bfr[4];
#pragma unroll
    for (int pass = 0; pass < 2; pass++)
#pragma unroll
      for (int ks = 0; ks < 2; ks++)
        bfr[pass * 2 + ks] = *(const bf16x8*)(Bl + (nf * 16 + col16) * 256 +
                                              ((pass * 128 + ks * 64 + quad * 16) ^ akey));
#pragma unroll
    for (int mi = 0; mi < 4; mi++)
#pragma unroll
      for (int pass = 0; pass < 2; pass++)
#pragma unroll
        for (int ks = 0; ks < 2; ks++)
          acc[mi][nf] = __builtin_amdgcn_mfma_f32_16x16x32_bf16(
              af[mi][ks], bfr[pass * 2 + ks], acc[mi][nf], 0, 0, 0);
  }

  __syncthreads();   // all A reads done; reuse A region as epilogue buffer

  // ---- epilogue: z from denom col (lane quad*16 holds col 64), swizzled LDS
  unsigned short* epi = (unsigned short*)smem;
#pragma unroll
  for (int mi = 0; mi < 4; mi++) {
#pragma unroll
    for (int rr = 0; rr < 4; rr++) {
      const float dv = __shfl(acc[mi][4][rr], lane & 48);
      const float z = 1.f / (dv + 1e-6f);
      const int row = wl0 + mi * 16 + quad * 4 + rr;
      const int key = (row & 7) << 4;
#pragma unroll
      for (int nf = 0; nf < 4; nf++)
        *(unsigned short*)((char*)epi + row * 128 +
                           (((nf * 16 + col16) * 2) ^ key)) =
            f2bf(acc[mi][nf][rr] * z);
    }
  }
  __syncthreads();

  // packed readback: thread -> one row chunk of 16 B per pass, 8 passes
#pragma unroll
  for (int r = 0; r < 8; r++) {
    const int row = r * 32 + (tid >> 3);
    const long l = lbase + row;
    const uint4 vv = *(const uint4*)((char*)epi + row * 128 +
                                     (((tid & 7) * 16) ^ ((row & 7) << 4)));
    *(uint4*)(out1 + (l * NBATCH + n) * (long)EMB + h * HDIM + (tid & 7) * 8) = vv;
  }
}

// ---------------------------------------------------------------------------
extern "C" void kernel_launch(void* const* d_in, const int* in_sizes, int n_in,
                              void* d_out, int out_size, void* d_ws, size_t ws_size,
                              hipStream_t stream) {
  const float* q  = (const float*)d_in[0];
  const float* k  = (const float*)d_in[1];
  const float* v  = (const float*)d_in[2];
  const float* Wq = (const float*)d_in[3];
  const float* bq = (const float*)d_in[4];
  const float* Wk = (const float*)d_in[5];
  const float* bk = (const float*)d_in[6];
  const float* Wv = (const float*)d_in[7];
  const float* bv = (const float*)d_in[8];
  const float* Wo = (const float*)d_in[9];
  const float* bo = (const float*)d_in[10];

  char* ws = (char*)d_ws;
  const size_t BUF = (size_t)MROWS * EMB * 2;  // 33,554,432 B
  unsigned short* T0  = (unsigned short*)(ws);              // A-staging / out1
  unsigned short* qf  = (unsigned short*)(ws + BUF);
  unsigned short* kf  = (unsigned short*)(ws + 2 * BUF);
  unsigned short* vp  = (unsigned short*)(ws + 3 * BUF);
  unsigned short* Wqb = (unsigned short*)(ws + 4 * BUF);
  unsigned short* Wkb = Wqb + (size_t)EMB * EMB;
  unsigned short* Wvb = Wkb + (size_t)EMB * EMB;
  unsigned short* Wob = Wvb + (size_t)EMB * EMB;
  float* kvp = (float*)(ws + 4 * BUF + 4 * (size_t)EMB * EMB * 2);
  float* ksp = kvp + (size_t)NCHUNK * NHG * HDIM * HDIM;

  const int nQKV = MROWS * EMB;     // 16,777,216
  const int nW   = EMB * EMB;       // 1,048,576

  // all 4 weight matrices -> bf16 in one dispatch
  convert_w4<<<dim3(nW / 1024, 4), 256, 0, stream>>>(Wq, Wk, Wv, Wo,
                                                     Wqb, Wkb, Wvb, Wob, nW);

  dim3 gg(MROWS / 256, EMB / 256), bb(512);

  // projections (T0 reused as bf16 A-staging between GEMMs; stream-ordered)
  convert_kernel<<<nQKV / 1024, 256, 0, stream>>>(q, T0, nQKV);
  gemm_bt<0><<<gg, bb, 0, stream>>>(T0, Wqb, bq, qf, MROWS, EMB, EMB);
  convert_kernel<<<nQKV / 1024, 256, 0, stream>>>(k, T0, nQKV);
  gemm_bt<0><<<gg, bb, 0, stream>>>(T0, Wkb, bk, kf, MROWS, EMB, EMB);
  convert_kernel<<<nQKV / 1024, 256, 0, stream>>>(v, T0, nQKV);
  gemm_bt<1><<<gg, bb, 0, stream>>>(T0, Wvb, bv, vp, MROWS, EMB, EMB);

  // attention state + output (out1 -> T0)
  kv_partial_kernel<<<dim3(NHG, NCHUNK), 256, 0, stream>>>(kf, vp, kvp, ksp);
  attn_out_kernel<<<dim3(NHG, L_SEQ / 256), 256, 0, stream>>>(qf, kvp, ksp, T0);

  // final projection -> fp32 output
  gemm_bt<2><<<gg, bb, 0, stream>>>(T0, Wob, bo, d_out, MROWS, EMB, EMB);
}